// Round 24
// baseline (839.445 us; speedup 1.0000x reference)
//
#include <hip/hip_runtime.h>
#include <hip/hip_bf16.h>

typedef __hip_bfloat16 bf16;

static __device__ __forceinline__ float b2f(bf16 v){ return __bfloat162float(v); }
static __device__ __forceinline__ float blo(unsigned u){ return __uint_as_float(u<<16); }
static __device__ __forceinline__ float bhi(unsigned u){ return __uint_as_float(u & 0xffff0000u); }
static __device__ __forceinline__ int clampi(int v, int lo, int hi){
  return v < lo ? lo : (v > hi ? hi : v);
}
static __device__ __forceinline__ float rw32(float v){
  #pragma unroll
  for (int m=16;m>=1;m>>=1) v += __shfl_xor(v,m,64);
  return v;
}
static __device__ __forceinline__ float rw64(float v){
  #pragma unroll
  for (int m=32;m>=1;m>>=1) v += __shfl_xor(v,m,64);
  return v;
}

constexpr int Nn = 30000;   // nodes
constexpr int E0 = 480000;  // edges (no self loops)
constexpr int EP = E0 + Nn; // edges incl self loops = 510000
constexpr int Gg = 128;     // graphs
constexpr int Vv = 10000;   // vocab size of emb

// ---------------- diagnostic flag (fp32 out) ----------------
__global__ void k_flag(float* __restrict__ out, float v){
  int t = blockIdx.x*blockDim.x + threadIdx.x;
  if (t < Gg*2) out[t] = v;
}

// ---------------- zero helper ----------------
__global__ void k_zeroi(int* __restrict__ a, int n){
  int t = blockIdx.x*blockDim.x + threadIdx.x;
  if (t < n) a[t] = 0;
}

// ---------------- CSR build (by dst) ----------------
__global__ void k_count(const int* __restrict__ ei, int* __restrict__ counts){
  int e = blockIdx.x*blockDim.x + threadIdx.x;
  if (e >= EP) return;
  int dst = (e < E0) ? clampi(ei[E0 + e], 0, Nn-1) : (e - E0);
  atomicAdd(&counts[dst], 1);
}

__global__ void k_scan(const int* __restrict__ counts, int* __restrict__ row_start){
  __shared__ int s[256];
  constexpr int CH = (Nn + 255) / 256;  // 118
  int tid = threadIdx.x;
  int base = tid*CH;
  int t_sum = 0;
  for (int j=0;j<CH;j++){ int i = base+j; if (i<Nn) t_sum += counts[i]; }
  s[tid] = t_sum; __syncthreads();
  for (int off=1; off<256; off<<=1){
    int v = (tid>=off) ? s[tid-off] : 0;
    __syncthreads();
    s[tid] += v; __syncthreads();
  }
  int run = s[tid] - t_sum; // exclusive prefix
  for (int j=0;j<CH;j++){ int i = base+j; if (i<Nn){ row_start[i] = run; run += counts[i]; } }
  if (tid == 255) row_start[Nn] = s[255];
}

__global__ void k_fill(const int* __restrict__ ei, const int* __restrict__ row_start,
                       int* __restrict__ cursor, int* __restrict__ csr_src){
  int e = blockIdx.x*blockDim.x + threadIdx.x;
  if (e >= EP) return;
  int src = (e < E0) ? clampi(ei[e],      0, Nn-1) : (e - E0);
  int dst = (e < E0) ? clampi(ei[E0 + e], 0, Nn-1) : (e - E0);
  int pos = atomicAdd(&cursor[dst], 1);
  int i = row_start[dst] + pos;
  if (i < 0 || i >= EP) return;
  csr_src[i] = src;
}

// ---------------- embedding gather (emb fp32 -> x bf16) ----------------
__global__ void k_gather(const float* __restrict__ emb, const int* __restrict__ ids,
                         bf16* __restrict__ x){
  int t = blockIdx.x*blockDim.x + threadIdx.x;
  if (t >= Nn*16) return;
  int n = t >> 4, c = t & 15;
  int id = clampi(ids[n], 0, Vv-1);
  x[t] = __float2bfloat16(emb[id*16 + c]);
}

// ---------------- fused dual linear, NM nodes per wave; x bf16 (uint4 chunks of 8) -------------
// (256,4): 4 waves/SIMD (VGPR budget 128) — audit says ~110 live regs, no spill expected.
// R19 lesson: spill signature = WRITE_SIZE balloon; fallback is (256,3).
template<int Fin, int Fout, int NM>
__global__ __launch_bounds__(256, 4)
void k_linear2(const bf16* __restrict__ x,
               const float* __restrict__ Wl, const float* __restrict__ bl,
               const float* __restrict__ Wr, const float* __restrict__ br,
               bf16* __restrict__ yl, bf16* __restrict__ yr){
  constexpr int NO = (Fout + 63)/64;
  int n0 = (blockIdx.x*(blockDim.x>>6) + (threadIdx.x>>6)) * NM;
  if (n0 >= Nn) return;
  int lane = threadIdx.x & 63;
  int nm = (Nn - n0 < NM) ? (Nn - n0) : NM;

  float accl[NM][NO], accr[NM][NO];
  #pragma unroll
  for (int m=0;m<NM;m++)
    #pragma unroll
    for (int j=0;j<NO;j++){
      int o = lane + 64*j;
      accl[m][j] = (o<Fout) ? bl[o] : 0.f;
      accr[m][j] = (o<Fout) ? br[o] : 0.f;
    }

  for (int k8=0; k8<Fin/8; k8++){
    uint4 xc[NM];
    #pragma unroll
    for (int m=0;m<NM;m++)
      xc[m] = (m<nm) ? ((const uint4*)(x + (size_t)(n0+m)*Fin))[k8]
                     : make_uint4(0,0,0,0);
    #pragma unroll
    for (int u=0;u<8;u++){
      int k = 8*k8 + u;
      float wl[NO], wr[NO];
      #pragma unroll
      for (int j=0;j<NO;j++){
        int o = lane + 64*j;
        wl[j] = (o<Fout) ? Wl[k*Fout+o] : 0.f;
        wr[j] = (o<Fout) ? Wr[k*Fout+o] : 0.f;
      }
      #pragma unroll
      for (int m=0;m<NM;m++){
        unsigned word = (u<2)?xc[m].x : (u<4)?xc[m].y : (u<6)?xc[m].z : xc[m].w;
        float xs = (u&1) ? bhi(word) : blo(word);
        #pragma unroll
        for (int j=0;j<NO;j++){
          accl[m][j] += xs*wl[j];
          accr[m][j] += xs*wr[j];
        }
      }
    }
  }

  #pragma unroll
  for (int m=0;m<NM;m++){
    if (m >= nm) break;
    #pragma unroll
    for (int j=0;j<NO;j++){
      int o = lane + 64*j;
      if (o < Fout){
        yl[(size_t)(n0+m)*Fout+o] = __float2bfloat16(accl[m][j]);
        yr[(size_t)(n0+m)*Fout+o] = __float2bfloat16(accr[m][j]);
      }
    }
  }
}

// ---------------- per-UN-edge group processing (loads + UN independent reduce chains) ----------
template<int H, int C, int S, int UN, bool MASK>
static __device__ __forceinline__
void edge_group(const bf16* __restrict__ xl, const int* __restrict__ csr_src,
                int i, int r1, int lane,
                const float* xrv, const float* attv,
                float* acc, float* ds){
  constexpr int HC = H*C;
  float xv[UN][S], wm[UN];
  #pragma unroll
  for (int u=0;u<UN;u++){
    int iu = i + u;
    int ii = MASK ? ((iu < r1) ? iu : (r1 - 1)) : iu;   // r1>r0 always (self-loop)
    wm[u] = MASK ? ((iu < r1) ? 1.f : 0.f) : 1.f;
    int src = clampi(csr_src[ii], 0, Nn-1);
    const bf16* row = xl + (size_t)src*HC;
    #pragma unroll
    for (int s=0;s<S;s++){
      int idx = lane + 64*s;
      xv[u][s] = (idx<HC) ? b2f(row[idx]) : 0.f;
    }
  }
  #pragma unroll
  for (int u=0;u<UN;u++){
    float t[S];
    #pragma unroll
    for (int s=0;s<S;s++){
      float v = xv[u][s] + xrv[s];
      v = (v > 0.f) ? v : 0.2f*v;          // leaky_relu 0.2
      t[s] = attv[s]*v;
    }
    float p[S];
    if constexpr (H==3 && C==32){
      float a = rw32(t[0]);                 // low: head0, high: head1
      float b = rw32(t[1]);                 // low: head2
      p[0] = __expf(a);
      p[1] = __expf(b);
    } else if constexpr (H==2 && C==96){
      bool low = lane < 32;
      float z0 = t[0] + (low ? t[1] : 0.f);
      float z1 = t[2] + (low ? 0.f : t[1]);
      float h0 = rw64(z0);
      float h1 = rw64(z1);
      float e0 = __expf(h0), e1 = __expf(h1);
      p[0] = e0;
      p[1] = low ? e0 : e1;
      p[2] = e1;
    } else {                                // H==1, C==64
      p[0] = __expf(rw64(t[0]));
    }
    #pragma unroll
    for (int s=0;s<S;s++){
      float pw = MASK ? p[s]*wm[u] : p[s];
      acc[s] += pw*xv[u][s];
      ds[s]  += pw;
    }
  }
}

// ---------------- FUSED attention: 8-edge main groups + masked 4-edge tail ----------------
template<int H, int C>
__global__ void k_fused(const bf16* __restrict__ xl, const bf16* __restrict__ xr,
                        const int* __restrict__ csr_src, const int* __restrict__ row_start,
                        const float* __restrict__ att, const float* __restrict__ bo,
                        bf16* __restrict__ y){
  constexpr int HC = H*C;
  constexpr int S = (HC + 63)/64;
  int n = blockIdx.x*(blockDim.x>>6) + (threadIdx.x>>6);
  if (n >= Nn) return;
  int lane = threadIdx.x & 63;
  int r0 = clampi(row_start[n],   0, EP);
  int r1 = clampi(row_start[n+1], 0, EP);

  float xrv[S], attv[S];
  #pragma unroll
  for (int s=0;s<S;s++){
    int idx = lane + 64*s;
    xrv[s]  = (idx<HC) ? b2f(xr[(size_t)n*HC + idx]) : 0.f;
    attv[s] = (idx<HC) ? att[idx] : 0.f;
  }

  float acc[S], ds[S];
  #pragma unroll
  for (int s=0;s<S;s++){ acc[s]=0.f; ds[s]=0.f; }

  int i = r0;
  for (; i + 8 <= r1; i += 8)
    edge_group<H,C,S,8,false>(xl, csr_src, i, r1, lane, xrv, attv, acc, ds);
  for (; i < r1; i += 4)
    edge_group<H,C,S,4,true>(xl, csr_src, i, r1, lane, xrv, attv, acc, ds);

  #pragma unroll
  for (int s=0;s<S;s++){
    int idx = lane + 64*s;
    if (idx < HC)
      y[(size_t)n*HC + idx] = __float2bfloat16(acc[s]/fmaxf(ds[s], 1e-30f) + bo[idx]);
  }
}

// ---------------- mean pool: one block per graph, batch sorted -> binary search, no atomics ----
__global__ void k_pool2(const bf16* __restrict__ x, const int* __restrict__ batch,
                        float* __restrict__ gsum, float* __restrict__ gcnt){
  __shared__ float sh[4][64];
  int g = blockIdx.x;
  int t = threadIdx.x;
  int c = t & 63;
  int w = t >> 6;
  int a = 0, b = Nn;
  while (a < b){ int m = (a+b)>>1; if (clampi(batch[m],0,Gg-1) < g) a = m+1; else b = m; }
  int lo = a;
  b = Nn;
  while (a < b){ int m = (a+b)>>1; if (clampi(batch[m],0,Gg-1) <= g) a = m+1; else b = m; }
  int hi = a;

  float s = 0.f;
  for (int n = lo + w; n < hi; n += 4)
    s += b2f(x[(size_t)n*64 + c]);
  sh[w][c] = s;
  __syncthreads();
  if (t < 64){
    gsum[g*64 + c] = sh[0][c] + sh[1][c] + sh[2][c] + sh[3][c];
    if (c == 0) gcnt[g] = (float)(hi - lo);
  }
}

// ---------------- classifier head: one block per graph (fp32 out) ----------------
__global__ void k_head(const float* __restrict__ gsum, const float* __restrict__ gcnt,
                       const float* __restrict__ demo,
                       const float* __restrict__ Wc1, const float* __restrict__ bc1,
                       const float* __restrict__ Wc2, const float* __restrict__ bc2,
                       float* __restrict__ out){
  __shared__ float h0[69];
  __shared__ float h1[32];
  int g = blockIdx.x;
  int t = threadIdx.x;
  float invc = 1.f / fmaxf(gcnt[g], 1.f);
  if (t < 64) h0[t] = gsum[g*64 + t] * invc;
  else if (t < 69) h0[t] = demo[g*5 + (t - 64)];
  __syncthreads();
  if (t < 32){
    float s = bc1[t];
    for (int k=0;k<69;k++) s += h0[k]*Wc1[k*32 + t];
    h1[t] = fmaxf(s, 0.f);
  }
  __syncthreads();
  if (t < 2){
    float s = bc2[t];
    for (int k=0;k<32;k++) s += h1[k]*Wc2[k*2 + t];
    out[g*2 + t] = s;
  }
}

extern "C" void kernel_launch(void* const* d_in, const int* in_sizes, int n_in,
                              void* d_out, int out_size, void* d_ws, size_t ws_size,
                              hipStream_t stream) {
  const float* emb  = (const float*)d_in[0];
  const float* Wl0  = (const float*)d_in[1];
  const float* bl0  = (const float*)d_in[2];
  const float* Wr0  = (const float*)d_in[3];
  const float* br0  = (const float*)d_in[4];
  const float* att0 = (const float*)d_in[5];
  const float* bo0  = (const float*)d_in[6];
  const float* Wl1  = (const float*)d_in[7];
  const float* bl1  = (const float*)d_in[8];
  const float* Wr1  = (const float*)d_in[9];
  const float* br1  = (const float*)d_in[10];
  const float* att1 = (const float*)d_in[11];
  const float* bo1  = (const float*)d_in[12];
  const float* Wl2  = (const float*)d_in[13];
  const float* bl2  = (const float*)d_in[14];
  const float* Wr2  = (const float*)d_in[15];
  const float* br2  = (const float*)d_in[16];
  const float* att2 = (const float*)d_in[17];
  const float* bo2  = (const float*)d_in[18];
  const float* Wc1  = (const float*)d_in[19];
  const float* bc1  = (const float*)d_in[20];
  const float* Wc2  = (const float*)d_in[21];
  const float* bc2  = (const float*)d_in[22];
  const float* demo = (const float*)d_in[23];
  const int* node_ids = (const int*)d_in[24];
  const int* ei       = (const int*)d_in[25];
  const int* batch    = (const int*)d_in[26];
  float* out = (float*)d_out;

  // ---- sentinel 4000: input ordering/sizes ----
  bool ok = (n_in == 27) && (out_size == Gg*2)
         && (in_sizes[0]  == Vv*16) && (in_sizes[1]  == 16*96)
         && (in_sizes[7]  == 96*192) && (in_sizes[13] == 192*64)
         && (in_sizes[19] == 69*32) && (in_sizes[23] == Gg*5)
         && (in_sizes[24] == Nn) && (in_sizes[25] == 2*E0) && (in_sizes[26] == Nn);
  if (!ok){ k_flag<<<1, 256, 0, stream>>>(out, 4000.f); return; }

  // ---- workspace layout (sentinel 5000 if too small) ----
  size_t need = 0;
  auto plan = [&](size_t bytes){ size_t r = need; need += (bytes + 255) & ~(size_t)255; return r; };
  size_t o_x      = plan((size_t)Nn*192*2);   // bf16 node features
  size_t o_xl     = plan((size_t)Nn*192*2);   // bf16 staging
  size_t o_xr     = plan((size_t)Nn*192*2);   // bf16 staging
  size_t o_counts = plan((size_t)Nn*4);
  size_t o_cursor = plan((size_t)Nn*4);
  size_t o_rs     = plan((size_t)(Nn+1)*4);
  size_t o_csrs   = plan((size_t)EP*4);
  size_t o_gsum   = plan((size_t)Gg*64*4);
  size_t o_gcnt   = plan((size_t)Gg*4);
  if (need > ws_size){ k_flag<<<1, 256, 0, stream>>>(out, 5000.f); return; }

  char* p = (char*)d_ws;
  bf16*  x      = (bf16*) (p + o_x);
  bf16*  xl     = (bf16*) (p + o_xl);
  bf16*  xr     = (bf16*) (p + o_xr);
  int*   counts = (int*)  (p + o_counts);
  int*   cursor = (int*)  (p + o_cursor);
  int*   row_start = (int*)(p + o_rs);
  int*   csr_src = (int*) (p + o_csrs);
  float* gsum   = (float*)(p + o_gsum);
  float* gcnt   = (float*)(p + o_gcnt);

  // ---- CSR build (once; shared by all 3 layers) ----
  k_zeroi<<<(Nn+255)/256, 256, 0, stream>>>(counts, Nn);
  k_zeroi<<<(Nn+255)/256, 256, 0, stream>>>(cursor, Nn);
  k_count<<<(EP+255)/256, 256, 0, stream>>>(ei, counts);
  k_scan<<<1, 256, 0, stream>>>(counts, row_start);
  k_fill<<<(EP+255)/256, 256, 0, stream>>>(ei, row_start, cursor, csr_src);

  // x0 = emb[node_ids] (bf16)
  k_gather<<<(Nn*16+255)/256, 256, 0, stream>>>(emb, node_ids, x);

  constexpr int NM = 8;
  int wgrid  = (Nn+3)/4;
  int lgrid8 = (Nn + 4*NM - 1)/(4*NM);

  // ---------- layer 0: Fin=16, H=3, C=32 ----------
  k_linear2<16,96,NM><<<lgrid8, 256, 0, stream>>>(x, Wl0, bl0, Wr0, br0, xl, xr);
  k_fused<3,32><<<wgrid, 256, 0, stream>>>(xl, xr, csr_src, row_start, att0, bo0, x);

  // ---------- layer 1: Fin=96, H=2, C=96 ----------
  k_linear2<96,192,NM><<<lgrid8, 256, 0, stream>>>(x, Wl1, bl1, Wr1, br1, xl, xr);
  k_fused<2,96><<<wgrid, 256, 0, stream>>>(xl, xr, csr_src, row_start, att1, bo1, x);

  // ---------- layer 2: Fin=192, H=1, C=64 ----------
  k_linear2<192,64,NM><<<lgrid8, 256, 0, stream>>>(x, Wl2, bl2, Wr2, br2, xl, xr);
  k_fused<1,64><<<wgrid, 256, 0, stream>>>(xl, xr, csr_src, row_start, att2, bo2, x);

  // ---------- mean pool (no atomics) + head ----------
  k_pool2<<<Gg, 256, 0, stream>>>(x, batch, gsum, gcnt);
  k_head<<<Gg, 128, 0, stream>>>(gsum, gcnt, demo, Wc1, bc1, Wc2, bc2, out);
}

// Round 25
// 509.401 us; speedup vs baseline: 1.6479x; 1.6479x over previous
//
#include <hip/hip_runtime.h>
#include <hip/hip_bf16.h>

typedef __hip_bfloat16 bf16;
typedef __attribute__((ext_vector_type(8))) short short8;
typedef __attribute__((ext_vector_type(4))) float f32x4;

static __device__ __forceinline__ float b2f(bf16 v){ return __bfloat162float(v); }
static __device__ __forceinline__ int clampi(int v, int lo, int hi){
  return v < lo ? lo : (v > hi ? hi : v);
}
static __device__ __forceinline__ float rw32(float v){
  #pragma unroll
  for (int m=16;m>=1;m>>=1) v += __shfl_xor(v,m,64);
  return v;
}
static __device__ __forceinline__ float rw64(float v){
  #pragma unroll
  for (int m=32;m>=1;m>>=1) v += __shfl_xor(v,m,64);
  return v;
}

constexpr int Nn = 30000;   // nodes
constexpr int E0 = 480000;  // edges (no self loops)
constexpr int EP = E0 + Nn; // edges incl self loops = 510000
constexpr int Gg = 128;     // graphs
constexpr int Vv = 10000;   // vocab size of emb

// ---------------- diagnostic flag (fp32 out) ----------------
__global__ void k_flag(float* __restrict__ out, float v){
  int t = blockIdx.x*blockDim.x + threadIdx.x;
  if (t < Gg*2) out[t] = v;
}

// ---------------- zero helper ----------------
__global__ void k_zeroi(int* __restrict__ a, int n){
  int t = blockIdx.x*blockDim.x + threadIdx.x;
  if (t < n) a[t] = 0;
}

// ---------------- CSR build (by dst) ----------------
__global__ void k_count(const int* __restrict__ ei, int* __restrict__ counts){
  int e = blockIdx.x*blockDim.x + threadIdx.x;
  if (e >= EP) return;
  int dst = (e < E0) ? clampi(ei[E0 + e], 0, Nn-1) : (e - E0);
  atomicAdd(&counts[dst], 1);
}

__global__ void k_scan(const int* __restrict__ counts, int* __restrict__ row_start){
  __shared__ int s[256];
  constexpr int CH = (Nn + 255) / 256;  // 118
  int tid = threadIdx.x;
  int base = tid*CH;
  int t_sum = 0;
  for (int j=0;j<CH;j++){ int i = base+j; if (i<Nn) t_sum += counts[i]; }
  s[tid] = t_sum; __syncthreads();
  for (int off=1; off<256; off<<=1){
    int v = (tid>=off) ? s[tid-off] : 0;
    __syncthreads();
    s[tid] += v; __syncthreads();
  }
  int run = s[tid] - t_sum; // exclusive prefix
  for (int j=0;j<CH;j++){ int i = base+j; if (i<Nn){ row_start[i] = run; run += counts[i]; } }
  if (tid == 255) row_start[Nn] = s[255];
}

__global__ void k_fill(const int* __restrict__ ei, const int* __restrict__ row_start,
                       int* __restrict__ cursor, int* __restrict__ csr_src){
  int e = blockIdx.x*blockDim.x + threadIdx.x;
  if (e >= EP) return;
  int src = (e < E0) ? clampi(ei[e],      0, Nn-1) : (e - E0);
  int dst = (e < E0) ? clampi(ei[E0 + e], 0, Nn-1) : (e - E0);
  int pos = atomicAdd(&cursor[dst], 1);
  int i = row_start[dst] + pos;
  if (i < 0 || i >= EP) return;
  csr_src[i] = src;
}

// ---------------- embedding gather (emb fp32 -> x bf16) ----------------
__global__ void k_gather(const float* __restrict__ emb, const int* __restrict__ ids,
                         bf16* __restrict__ x){
  int t = blockIdx.x*blockDim.x + threadIdx.x;
  if (t >= Nn*16) return;
  int n = t >> 4, c = t & 15;
  int id = clampi(ids[n], 0, Vv-1);
  x[t] = __float2bfloat16(emb[id*16 + c]);
}

// ---------------- pack W [K][F] fp32 -> Wb [F][Kp] bf16 (transpose, K zero-padded) ----------
__global__ void k_packW(const float* __restrict__ W, bf16* __restrict__ Wb,
                        int K, int F, int Kp){
  int t = blockIdx.x*blockDim.x + threadIdx.x;
  if (t >= F*Kp) return;
  int o = t / Kp, k = t % Kp;
  float v = (k < K) ? W[k*F + o] : 0.f;
  Wb[t] = __float2bfloat16(v);
}

// ---------------- MFMA dual linear: one wave = 16 nodes x 16 outputs ----------------
// A: x[m=lane&15][k=quad*8+j] (16B/lane). B: Wb[n=lane&15][k=quad*8+j] (pre-transposed).
// D: y[row=quad*4+reg][col=lane&15]. K=16 padded to 32 (Kp).
template<int K, int Kp, int Fout>
__global__ void k_linmfma(const bf16* __restrict__ x,
                          const bf16* __restrict__ Wbl, const float* __restrict__ bl,
                          const bf16* __restrict__ Wbr, const float* __restrict__ br,
                          bf16* __restrict__ yl, bf16* __restrict__ yr){
  constexpr int OT = Fout/16;
  constexpr int KSTEPS = Kp/32;
  int w = blockIdx.x*(blockDim.x>>6) + (threadIdx.x>>6);
  constexpr int MT = Nn/16;              // 1875 (exact)
  if (w >= MT * 2*OT) return;
  int mt  = w / (2*OT);
  int ot2 = w % (2*OT);
  bool isl = ot2 < OT;
  int o0 = (isl ? ot2 : ot2 - OT) * 16;
  const bf16*  Wb   = isl ? Wbl : Wbr;
  const float* bias = isl ? bl  : br;
  bf16*        y    = isl ? yl  : yr;

  int lane = threadIdx.x & 63;
  int l16  = lane & 15;
  int quad = lane >> 4;

  const bf16* arow = x  + (size_t)(mt*16 + l16)*K;
  const bf16* brow = Wb + (size_t)(o0 + l16)*Kp;

  f32x4 acc = {0.f,0.f,0.f,0.f};
  #pragma unroll
  for (int ks=0; ks<KSTEPS; ks++){
    int k0 = ks*32 + quad*8;
    short8 a;
    if (K == Kp || k0 < K) a = *(const short8*)(arow + k0);
    else                   a = short8{0,0,0,0,0,0,0,0};
    short8 b = *(const short8*)(brow + k0);
    acc = __builtin_amdgcn_mfma_f32_16x16x32_bf16(a, b, acc, 0, 0, 0);
  }

  float bo_ = bias[o0 + l16];
  #pragma unroll
  for (int r=0;r<4;r++){
    int m = mt*16 + quad*4 + r;
    y[(size_t)m*Fout + o0 + l16] = __float2bfloat16(acc[r] + bo_);
  }
}

// ---------------- per-UN-edge group processing (loads + UN independent reduce chains) ----------
template<int H, int C, int S, int UN, bool MASK>
static __device__ __forceinline__
void edge_group(const bf16* __restrict__ xl, const int* __restrict__ csr_src,
                int i, int r1, int lane,
                const float* xrv, const float* attv,
                float* acc, float* ds){
  constexpr int HC = H*C;
  float xv[UN][S], wm[UN];
  #pragma unroll
  for (int u=0;u<UN;u++){
    int iu = i + u;
    int ii = MASK ? ((iu < r1) ? iu : (r1 - 1)) : iu;   // r1>r0 always (self-loop)
    wm[u] = MASK ? ((iu < r1) ? 1.f : 0.f) : 1.f;
    int src = clampi(csr_src[ii], 0, Nn-1);
    const bf16* row = xl + (size_t)src*HC;
    #pragma unroll
    for (int s=0;s<S;s++){
      int idx = lane + 64*s;
      xv[u][s] = (idx<HC) ? b2f(row[idx]) : 0.f;
    }
  }
  #pragma unroll
  for (int u=0;u<UN;u++){
    float t[S];
    #pragma unroll
    for (int s=0;s<S;s++){
      float v = xv[u][s] + xrv[s];
      v = (v > 0.f) ? v : 0.2f*v;          // leaky_relu 0.2
      t[s] = attv[s]*v;
    }
    float p[S];
    if constexpr (H==3 && C==32){
      float a = rw32(t[0]);                 // low: head0, high: head1
      float b = rw32(t[1]);                 // low: head2
      p[0] = __expf(a);
      p[1] = __expf(b);
    } else if constexpr (H==2 && C==96){
      bool low = lane < 32;
      float z0 = t[0] + (low ? t[1] : 0.f);
      float z1 = t[2] + (low ? 0.f : t[1]);
      float h0 = rw64(z0);
      float h1 = rw64(z1);
      float e0 = __expf(h0), e1 = __expf(h1);
      p[0] = e0;
      p[1] = low ? e0 : e1;
      p[2] = e1;
    } else {                                // H==1, C==64
      p[0] = __expf(rw64(t[0]));
    }
    #pragma unroll
    for (int s=0;s<S;s++){
      float pw = MASK ? p[s]*wm[u] : p[s];
      acc[s] += pw*xv[u][s];
      ds[s]  += pw;
    }
  }
}

// ---------------- FUSED attention: 8-edge main groups + masked 4-edge tail ----------------
template<int H, int C>
__global__ void k_fused(const bf16* __restrict__ xl, const bf16* __restrict__ xr,
                        const int* __restrict__ csr_src, const int* __restrict__ row_start,
                        const float* __restrict__ att, const float* __restrict__ bo,
                        bf16* __restrict__ y){
  constexpr int HC = H*C;
  constexpr int S = (HC + 63)/64;
  int n = blockIdx.x*(blockDim.x>>6) + (threadIdx.x>>6);
  if (n >= Nn) return;
  int lane = threadIdx.x & 63;
  int r0 = clampi(row_start[n],   0, EP);
  int r1 = clampi(row_start[n+1], 0, EP);

  float xrv[S], attv[S];
  #pragma unroll
  for (int s=0;s<S;s++){
    int idx = lane + 64*s;
    xrv[s]  = (idx<HC) ? b2f(xr[(size_t)n*HC + idx]) : 0.f;
    attv[s] = (idx<HC) ? att[idx] : 0.f;
  }

  float acc[S], ds[S];
  #pragma unroll
  for (int s=0;s<S;s++){ acc[s]=0.f; ds[s]=0.f; }

  int i = r0;
  for (; i + 8 <= r1; i += 8)
    edge_group<H,C,S,8,false>(xl, csr_src, i, r1, lane, xrv, attv, acc, ds);
  for (; i < r1; i += 4)
    edge_group<H,C,S,4,true>(xl, csr_src, i, r1, lane, xrv, attv, acc, ds);

  #pragma unroll
  for (int s=0;s<S;s++){
    int idx = lane + 64*s;
    if (idx < HC)
      y[(size_t)n*HC + idx] = __float2bfloat16(acc[s]/fmaxf(ds[s], 1e-30f) + bo[idx]);
  }
}

// ---------------- mean pool: one block per graph, batch sorted -> binary search, no atomics ----
__global__ void k_pool2(const bf16* __restrict__ x, const int* __restrict__ batch,
                        float* __restrict__ gsum, float* __restrict__ gcnt){
  __shared__ float sh[4][64];
  int g = blockIdx.x;
  int t = threadIdx.x;
  int c = t & 63;
  int w = t >> 6;
  int a = 0, b = Nn;
  while (a < b){ int m = (a+b)>>1; if (clampi(batch[m],0,Gg-1) < g) a = m+1; else b = m; }
  int lo = a;
  b = Nn;
  while (a < b){ int m = (a+b)>>1; if (clampi(batch[m],0,Gg-1) <= g) a = m+1; else b = m; }
  int hi = a;

  float s = 0.f;
  for (int n = lo + w; n < hi; n += 4)
    s += b2f(x[(size_t)n*64 + c]);
  sh[w][c] = s;
  __syncthreads();
  if (t < 64){
    gsum[g*64 + c] = sh[0][c] + sh[1][c] + sh[2][c] + sh[3][c];
    if (c == 0) gcnt[g] = (float)(hi - lo);
  }
}

// ---------------- classifier head: one block per graph (fp32 out) ----------------
__global__ void k_head(const float* __restrict__ gsum, const float* __restrict__ gcnt,
                       const float* __restrict__ demo,
                       const float* __restrict__ Wc1, const float* __restrict__ bc1,
                       const float* __restrict__ Wc2, const float* __restrict__ bc2,
                       float* __restrict__ out){
  __shared__ float h0[69];
  __shared__ float h1[32];
  int g = blockIdx.x;
  int t = threadIdx.x;
  float invc = 1.f / fmaxf(gcnt[g], 1.f);
  if (t < 64) h0[t] = gsum[g*64 + t] * invc;
  else if (t < 69) h0[t] = demo[g*5 + (t - 64)];
  __syncthreads();
  if (t < 32){
    float s = bc1[t];
    for (int k=0;k<69;k++) s += h0[k]*Wc1[k*32 + t];
    h1[t] = fmaxf(s, 0.f);
  }
  __syncthreads();
  if (t < 2){
    float s = bc2[t];
    for (int k=0;k<32;k++) s += h1[k]*Wc2[k*2 + t];
    out[g*2 + t] = s;
  }
}

extern "C" void kernel_launch(void* const* d_in, const int* in_sizes, int n_in,
                              void* d_out, int out_size, void* d_ws, size_t ws_size,
                              hipStream_t stream) {
  const float* emb  = (const float*)d_in[0];
  const float* Wl0  = (const float*)d_in[1];
  const float* bl0  = (const float*)d_in[2];
  const float* Wr0  = (const float*)d_in[3];
  const float* br0  = (const float*)d_in[4];
  const float* att0 = (const float*)d_in[5];
  const float* bo0  = (const float*)d_in[6];
  const float* Wl1  = (const float*)d_in[7];
  const float* bl1  = (const float*)d_in[8];
  const float* Wr1  = (const float*)d_in[9];
  const float* br1  = (const float*)d_in[10];
  const float* att1 = (const float*)d_in[11];
  const float* bo1  = (const float*)d_in[12];
  const float* Wl2  = (const float*)d_in[13];
  const float* bl2  = (const float*)d_in[14];
  const float* Wr2  = (const float*)d_in[15];
  const float* br2  = (const float*)d_in[16];
  const float* att2 = (const float*)d_in[17];
  const float* bo2  = (const float*)d_in[18];
  const float* Wc1  = (const float*)d_in[19];
  const float* bc1  = (const float*)d_in[20];
  const float* Wc2  = (const float*)d_in[21];
  const float* bc2  = (const float*)d_in[22];
  const float* demo = (const float*)d_in[23];
  const int* node_ids = (const int*)d_in[24];
  const int* ei       = (const int*)d_in[25];
  const int* batch    = (const int*)d_in[26];
  float* out = (float*)d_out;

  // ---- sentinel 4000: input ordering/sizes ----
  bool ok = (n_in == 27) && (out_size == Gg*2)
         && (in_sizes[0]  == Vv*16) && (in_sizes[1]  == 16*96)
         && (in_sizes[7]  == 96*192) && (in_sizes[13] == 192*64)
         && (in_sizes[19] == 69*32) && (in_sizes[23] == Gg*5)
         && (in_sizes[24] == Nn) && (in_sizes[25] == 2*E0) && (in_sizes[26] == Nn);
  if (!ok){ k_flag<<<1, 256, 0, stream>>>(out, 4000.f); return; }

  // ---- workspace layout (sentinel 5000 if too small) ----
  size_t need = 0;
  auto plan = [&](size_t bytes){ size_t r = need; need += (bytes + 255) & ~(size_t)255; return r; };
  size_t o_x      = plan((size_t)Nn*192*2);   // bf16 node features
  size_t o_xl     = plan((size_t)Nn*192*2);   // bf16 staging
  size_t o_xr     = plan((size_t)Nn*192*2);   // bf16 staging
  size_t o_counts = plan((size_t)Nn*4);
  size_t o_cursor = plan((size_t)Nn*4);
  size_t o_rs     = plan((size_t)(Nn+1)*4);
  size_t o_csrs   = plan((size_t)EP*4);
  size_t o_gsum   = plan((size_t)Gg*64*4);
  size_t o_gcnt   = plan((size_t)Gg*4);
  size_t o_wb0l   = plan((size_t)96*32*2);    // packed W (bf16, transposed, K padded)
  size_t o_wb0r   = plan((size_t)96*32*2);
  size_t o_wb1l   = plan((size_t)192*96*2);
  size_t o_wb1r   = plan((size_t)192*96*2);
  size_t o_wb2l   = plan((size_t)64*192*2);
  size_t o_wb2r   = plan((size_t)64*192*2);
  if (need > ws_size){ k_flag<<<1, 256, 0, stream>>>(out, 5000.f); return; }

  char* p = (char*)d_ws;
  bf16*  x      = (bf16*) (p + o_x);
  bf16*  xl     = (bf16*) (p + o_xl);
  bf16*  xr     = (bf16*) (p + o_xr);
  int*   counts = (int*)  (p + o_counts);
  int*   cursor = (int*)  (p + o_cursor);
  int*   row_start = (int*)(p + o_rs);
  int*   csr_src = (int*) (p + o_csrs);
  float* gsum   = (float*)(p + o_gsum);
  float* gcnt   = (float*)(p + o_gcnt);
  bf16*  wb0l   = (bf16*) (p + o_wb0l);
  bf16*  wb0r   = (bf16*) (p + o_wb0r);
  bf16*  wb1l   = (bf16*) (p + o_wb1l);
  bf16*  wb1r   = (bf16*) (p + o_wb1r);
  bf16*  wb2l   = (bf16*) (p + o_wb2l);
  bf16*  wb2r   = (bf16*) (p + o_wb2r);

  // ---- CSR build (once; shared by all 3 layers) ----
  k_zeroi<<<(Nn+255)/256, 256, 0, stream>>>(counts, Nn);
  k_zeroi<<<(Nn+255)/256, 256, 0, stream>>>(cursor, Nn);
  k_count<<<(EP+255)/256, 256, 0, stream>>>(ei, counts);
  k_scan<<<1, 256, 0, stream>>>(counts, row_start);
  k_fill<<<(EP+255)/256, 256, 0, stream>>>(ei, row_start, cursor, csr_src);

  // ---- pack weights for MFMA (transpose + bf16 + K-pad) ----
  k_packW<<<(96*32+255)/256,  256, 0, stream>>>(Wl0, wb0l, 16, 96, 32);
  k_packW<<<(96*32+255)/256,  256, 0, stream>>>(Wr0, wb0r, 16, 96, 32);
  k_packW<<<(192*96+255)/256, 256, 0, stream>>>(Wl1, wb1l, 96, 192, 96);
  k_packW<<<(192*96+255)/256, 256, 0, stream>>>(Wr1, wb1r, 96, 192, 96);
  k_packW<<<(64*192+255)/256, 256, 0, stream>>>(Wl2, wb2l, 192, 64, 192);
  k_packW<<<(64*192+255)/256, 256, 0, stream>>>(Wr2, wb2r, 192, 64, 192);

  // x0 = emb[node_ids] (bf16)
  k_gather<<<(Nn*16+255)/256, 256, 0, stream>>>(emb, node_ids, x);

  int wgrid = (Nn+3)/4;
  constexpr int MT = Nn/16;  // 1875

  // ---------- layer 0: Fin=16 (pad 32), H=3, C=32 (Fout=96 -> 6 o-tiles x2) ----------
  k_linmfma<16,32,96><<<(MT*12+3)/4, 256, 0, stream>>>(x, wb0l, bl0, wb0r, br0, xl, xr);
  k_fused<3,32><<<wgrid, 256, 0, stream>>>(xl, xr, csr_src, row_start, att0, bo0, x);

  // ---------- layer 1: Fin=96, H=2, C=96 (Fout=192 -> 12 o-tiles x2) ----------
  k_linmfma<96,96,192><<<(MT*24+3)/4, 256, 0, stream>>>(x, wb1l, bl1, wb1r, br1, xl, xr);
  k_fused<2,96><<<wgrid, 256, 0, stream>>>(xl, xr, csr_src, row_start, att1, bo1, x);

  // ---------- layer 2: Fin=192, H=1, C=64 (Fout=64 -> 4 o-tiles x2) ----------
  k_linmfma<192,192,64><<<(MT*8+3)/4, 256, 0, stream>>>(x, wb2l, bl2, wb2r, br2, xl, xr);
  k_fused<1,64><<<wgrid, 256, 0, stream>>>(xl, xr, csr_src, row_start, att2, bo2, x);

  // ---------- mean pool (no atomics) + head ----------
  k_pool2<<<Gg, 256, 0, stream>>>(x, batch, gsum, gcnt);
  k_head<<<Gg, 128, 0, stream>>>(gsum, gcnt, demo, Wc1, bc1, Wc2, bc2, out);
}